// Round 11
// baseline (132.486 us; speedup 1.0000x reference)
//
#include <hip/hip_runtime.h>
#include <hip/hip_bf16.h>

#define B 128
#define N 1024
#define L 512
#define D 64

typedef float f32x4 __attribute__((ext_vector_type(4)));
typedef short bf16x8 __attribute__((ext_vector_type(8)));

// 8 fp32 -> 8 bf16 (RNE) via packed HW cvt
__device__ inline bf16x8 cvt8(float4 f0, float4 f1) {
    union { __hip_bfloat162 h2[4]; bf16x8 v; } u;
    u.h2[0] = __float22bfloat162_rn(make_float2(f0.x, f0.y));
    u.h2[1] = __float22bfloat162_rn(make_float2(f0.z, f0.w));
    u.h2[2] = __float22bfloat162_rn(make_float2(f1.x, f1.y));
    u.h2[3] = __float22bfloat162_rn(make_float2(f1.z, f1.w));
    return u.v;
}

// ws layout (bytes):
//   [0)     float partials[1536]
//   [6144)  int   cnts[2*B]
//   [8192)  unsigned short Ibf[B*L*D]   (8.4 MB, ONLY if ws_size permits)
#define WS_NEED_PRE (8192 + (size_t)B * L * D * 2)

__global__ __launch_bounds__(64) void cnts_kernel(
        const float* __restrict__ tmask, const float* __restrict__ imask,
        int* __restrict__ cnts) {
    int row = blockIdx.x;          // 0..2B-1
    int lane = threadIdx.x;        // 64
    float s = 0.f;
    if (row < B) {
        const float* p = tmask + (size_t)row * N;
        for (int i = lane; i < N; i += 64) s += p[i];
    } else {
        const float* p = imask + (size_t)(row - B) * L;
        for (int i = lane; i < L; i += 64) s += p[i];
    }
    for (int off = 32; off > 0; off >>= 1) s += __shfl_down(s, off);
    if (lane == 0) cnts[row] = (int)(s + 0.5f);
}

// I (fp32 row-major) -> Ibf (bf16, fragment order). Linear property:
// byte offset of (tile rt, half h, lane) = rt*2048 + h*1024 + lane*16,
// where tile rt covers regions rt*16..+16, lane unit = region rt*16+(lane&15),
// d-range h*32+(lane>>4)*8..+8. Exactly the MFMA B-fragment per lane.
__global__ __launch_bounds__(256) void prep_kernel(
        const float* __restrict__ I, unsigned short* __restrict__ Ibf) {
    int blk = blockIdx.x;          // b*8 + k, 0..1023
    int tid = threadIdx.x;
    const float* src = I + (size_t)blk * 64 * D;
    unsigned short* dst = Ibf + (size_t)blk * 4096;
#pragma unroll
    for (int j = 0; j < 2; ++j) {
        int si = tid + j * 256;    // 32B source unit: region si>>3, seg si&7
        int r = si >> 3, seg = si & 7;
        const float4* p = (const float4*)(src + (size_t)si * 8);
        bf16x8 v = cvt8(p[0], p[1]);
        int h = seg >> 2, qq = seg & 3;
        int ci = ((r >> 4) * 2 + h) * 64 + qq * 16 + (r & 15);
        *(bf16x8*)(dst + (size_t)ci * 8) = v;
    }
}

// PRE path: NO LDS, NO barriers in the main loop. B-fragments are loaded
// per-lane straight from pre-swizzled Ibf (coalesced dwordx4; addresses are
// identical across the block's 4 waves -> L1 reuse; Ibf is L2-resident).
// Depth-2 register pipeline hides L2 latency; 4 blocks/CU at (256,4) adds TLP.
// Removes the per-chunk vmcnt(0)+s_barrier drain that bounded the LDS path.
// non-PRE fallback: R10's verified LDS double-buffer path.
template <bool PRE>
__global__ __launch_bounds__(256, 4) void sim_kernel(
        const float* __restrict__ T, const float* __restrict__ I,
        const unsigned short* __restrict__ Ibf, const int* __restrict__ cnts,
        const int* __restrict__ Iimp, const int* __restrict__ Simp,
        float* __restrict__ partials) {
    int blk = blockIdx.x;          // 0..1535
    int chunk = blk & 3;
    int bs = blk >> 2;
    int b = bs & (B - 1);
    int s = bs >> 7;
    int Tb = b, Ib = b;
    if (s == 1) Tb = Simp[b];
    else if (s == 2) Ib = Iimp[b];
    int ntok = cnts[Tb];
    int nreg = cnts[B + Ib];

    int tid = threadIdx.x;
    int tok0 = chunk * 256;
    if (tok0 >= ntok) {            // empty chunk: ~100 cycles and gone
        if (tid == 0) partials[blk] = 0.f;
        return;
    }

    int w = tid >> 6;
    int lane = tid & 63;
    int q = lane >> 4;
    int c = lane & 15;

    __shared__ float wsum[4];

    // ---- A fragments: 4 token tiles x 2 K-halves ----
    int wt0 = tok0 + w * 64;
    bf16x8 afrag[4][2];
#pragma unroll
    for (int tt = 0; tt < 4; ++tt) {
        const float* trow = T + ((size_t)Tb * N + wt0 + tt * 16 + c) * D;
#pragma unroll
        for (int h = 0; h < 2; ++h) {
            const float4* p = (const float4*)(trow + h * 32 + q * 8);
            afrag[tt][h] = cvt8(p[0], p[1]);
        }
    }

    float mx[4][4];
#pragma unroll
    for (int tt = 0; tt < 4; ++tt)
#pragma unroll
        for (int i = 0; i < 4; ++i) mx[tt][i] = -3.0e38f;

    int nrt = (nreg + 15) >> 4;    // region tiles of 16
    int prem = nreg & 15;

    if (PRE) {
        // ---- barrier-free register-pipelined main loop ----
        const char* imgL = (const char*)(Ibf + (size_t)Ib * L * D) + (size_t)lane * 16;
        bf16x8 cb0 = *(const bf16x8*)(imgL);
        bf16x8 cb1 = *(const bf16x8*)(imgL + 1024);
#pragma unroll 2
        for (int rt = 0; rt < nrt; ++rt) {
            bf16x8 nb0 = cb0, nb1 = cb1;
            if (rt + 1 < nrt) {    // next tile's loads in flight over MFMAs
                const char* p = imgL + (size_t)(rt + 1) * 2048;
                nb0 = *(const bf16x8*)(p);
                nb1 = *(const bf16x8*)(p + 1024);
            }
            bool vld = (rt + 1 < nrt) || (prem == 0) || (c < prem);
#pragma unroll
            for (int tt = 0; tt < 4; ++tt) {
                f32x4 acc = {0.f, 0.f, 0.f, 0.f};
                acc = __builtin_amdgcn_mfma_f32_16x16x32_bf16(afrag[tt][0], cb0, acc, 0, 0, 0);
                acc = __builtin_amdgcn_mfma_f32_16x16x32_bf16(afrag[tt][1], cb1, acc, 0, 0, 0);
                if (vld) {
#pragma unroll
                    for (int i = 0; i < 4; ++i) mx[tt][i] = fmaxf(mx[tt][i], acc[i]);
                }
            }
            cb0 = nb0; cb1 = nb1;
        }
    } else {
        // ---- fallback: R10's LDS double-buffered path (inline fp32+cvt) ----
        __shared__ unsigned short ldsI[2][64 * D];
        int r_loc[2], db_loc[2];
#pragma unroll
        for (int j = 0; j < 2; ++j) {
            int ci = tid + j * 256;
            int g = ci >> 6, ln = ci & 63;
            r_loc[j] = (g >> 1) * 16 + (ln & 15);
            db_loc[j] = (g & 1) * 32 + (ln >> 4) * 8;
        }
        int nchunks = (nreg + 63) >> 6;
        const float* Ibase = I + (size_t)Ib * L * D;
        float4 pf[4];
        auto issue = [&](int k) {
            int rbase = k * 64;
#pragma unroll
            for (int j = 0; j < 2; ++j) {
                int r = rbase + r_loc[j];
                if (r < nreg) {
                    const float4* p = (const float4*)(Ibase + (size_t)r * D + db_loc[j]);
                    pf[2 * j] = p[0];
                    pf[2 * j + 1] = p[1];
                } else {
                    pf[2 * j] = make_float4(0.f, 0.f, 0.f, 0.f);
                    pf[2 * j + 1] = make_float4(0.f, 0.f, 0.f, 0.f);
                }
            }
        };
        auto store = [&](int k) {
            char* bufb = (char*)&ldsI[k & 1][0];
#pragma unroll
            for (int j = 0; j < 2; ++j) {
                int ci = tid + j * 256;
                *(bf16x8*)(bufb + (size_t)ci * 16) = cvt8(pf[2 * j], pf[2 * j + 1]);
            }
        };
        issue(0); store(0); __syncthreads();
        for (int k = 0; k < nchunks; ++k) {
            if (k + 1 < nchunks) issue(k + 1);
            const char* base = (const char*)&ldsI[k & 1][0] + (size_t)lane * 16;
            int nvalid = nreg - k * 64;
            if (nvalid > 64) nvalid = 64;
            int nft = nvalid >> 4, prem2 = nvalid & 15;
            for (int rt = 0; rt < nft; ++rt) {
                bf16x8 b0 = *(const bf16x8*)(base + (size_t)(rt * 2 + 0) * 1024);
                bf16x8 b1 = *(const bf16x8*)(base + (size_t)(rt * 2 + 1) * 1024);
#pragma unroll
                for (int tt = 0; tt < 4; ++tt) {
                    f32x4 acc = {0.f, 0.f, 0.f, 0.f};
                    acc = __builtin_amdgcn_mfma_f32_16x16x32_bf16(afrag[tt][0], b0, acc, 0, 0, 0);
                    acc = __builtin_amdgcn_mfma_f32_16x16x32_bf16(afrag[tt][1], b1, acc, 0, 0, 0);
#pragma unroll
                    for (int i = 0; i < 4; ++i) mx[tt][i] = fmaxf(mx[tt][i], acc[i]);
                }
            }
            if (prem2) {
                bf16x8 b0 = *(const bf16x8*)(base + (size_t)(nft * 2 + 0) * 1024);
                bf16x8 b1 = *(const bf16x8*)(base + (size_t)(nft * 2 + 1) * 1024);
                bool valid = c < prem2;
#pragma unroll
                for (int tt = 0; tt < 4; ++tt) {
                    f32x4 acc = {0.f, 0.f, 0.f, 0.f};
                    acc = __builtin_amdgcn_mfma_f32_16x16x32_bf16(afrag[tt][0], b0, acc, 0, 0, 0);
                    acc = __builtin_amdgcn_mfma_f32_16x16x32_bf16(afrag[tt][1], b1, acc, 0, 0, 0);
                    if (valid) {
#pragma unroll
                        for (int i = 0; i < 4; ++i) mx[tt][i] = fmaxf(mx[tt][i], acc[i]);
                    }
                }
            }
            if (k + 1 < nchunks) { store(k + 1); __syncthreads(); }
        }
    }

    // ---- cross-lane max over 16 region-cols ----
#pragma unroll
    for (int m = 1; m < 16; m <<= 1) {
#pragma unroll
        for (int tt = 0; tt < 4; ++tt)
#pragma unroll
            for (int i = 0; i < 4; ++i)
                mx[tt][i] = fmaxf(mx[tt][i], __shfl_xor(mx[tt][i], m));
    }

    // ---- masked token sum (C layout: row = q*4 + i) ----
    float bsum = 0.f;
    if (c == 0) {
#pragma unroll
        for (int tt = 0; tt < 4; ++tt)
#pragma unroll
            for (int i = 0; i < 4; ++i) {
                int row = wt0 + tt * 16 + q * 4 + i;
                if (row < ntok) bsum += mx[tt][i];
            }
    }
    for (int off = 32; off > 0; off >>= 1) bsum += __shfl_down(bsum, off);
    if (lane == 0) wsum[w] = bsum;
    __syncthreads();
    if (tid == 0)
        partials[blk] = (wsum[0] + wsum[1] + wsum[2] + wsum[3]) / (float)ntok;
}

// 1 block x 384 threads: fold 1536 partials -> 384 sims -> hinge -> loss
__global__ void loss_kernel(const float* __restrict__ partials,
                            float* __restrict__ out) {
    int tid = threadIdx.x;  // 0..383
    __shared__ float simsL[384];
    __shared__ float w6[6];
    const float4* p4 = (const float4*)partials;
    float4 v = p4[tid];
    simsL[tid] = v.x + v.y + v.z + v.w;
    __syncthreads();
    float per = 0.f;
    if (tid < B) {
        float anc  = simsL[tid];
        float simp = simsL[B + tid];
        float iimp = simsL[2 * B + tid];
        per = fmaxf(1.f + iimp - anc, 0.f) + fmaxf(1.f + simp - anc, 0.f);
    }
    for (int off = 32; off > 0; off >>= 1) per += __shfl_down(per, off);
    if ((tid & 63) == 0) w6[tid >> 6] = per;
    __syncthreads();
    if (tid == 0)
        out[0] = (w6[0] + w6[1] + w6[2] + w6[3] + w6[4] + w6[5]) / (float)B;
}

extern "C" void kernel_launch(void* const* d_in, const int* in_sizes, int n_in,
                              void* d_out, int out_size, void* d_ws, size_t ws_size,
                              hipStream_t stream) {
    const float* T     = (const float*)d_in[0];
    const float* I     = (const float*)d_in[1];
    const float* tmask = (const float*)d_in[2];
    const float* imask = (const float*)d_in[3];
    const int*   Iimp  = (const int*)d_in[4];
    const int*   Simp  = (const int*)d_in[5];

    float* partials = (float*)d_ws;                          // 1536 f
    int*   cnts     = (int*)((char*)d_ws + 6144);            // 256 i
    unsigned short* Ibf = (unsigned short*)((char*)d_ws + 8192);

    cnts_kernel<<<2 * B, 64, 0, stream>>>(tmask, imask, cnts);
    if (ws_size >= WS_NEED_PRE) {
        prep_kernel<<<B * 8, 256, 0, stream>>>(I, Ibf);
        sim_kernel<true><<<3 * B * 4, 256, 0, stream>>>(T, I, Ibf, cnts, Iimp, Simp, partials);
    } else {
        sim_kernel<false><<<3 * B * 4, 256, 0, stream>>>(T, I, Ibf, cnts, Iimp, Simp, partials);
    }
    loss_kernel<<<1, 384, 0, stream>>>(partials, (float*)d_out);
}

// Round 12
// 128.099 us; speedup vs baseline: 1.0342x; 1.0342x over previous
//
#include <hip/hip_runtime.h>
#include <hip/hip_bf16.h>

#define B 128
#define N 1024
#define L 512
#define D 64
#define TT 6                 // token tiles per wave (96 tokens)
#define TOKBLK 384           // tokens per block (4 waves)
#define NCH 3                // token chunks per (s,b):  3*384 >= 1024

typedef float f32x4 __attribute__((ext_vector_type(4)));
typedef short bf16x8 __attribute__((ext_vector_type(8)));

// 8 fp32 -> 8 bf16 (RNE) via packed HW cvt
__device__ inline bf16x8 cvt8(float4 f0, float4 f1) {
    union { __hip_bfloat162 h2[4]; bf16x8 v; } u;
    u.h2[0] = __float22bfloat162_rn(make_float2(f0.x, f0.y));
    u.h2[1] = __float22bfloat162_rn(make_float2(f0.z, f0.w));
    u.h2[2] = __float22bfloat162_rn(make_float2(f1.x, f1.y));
    u.h2[3] = __float22bfloat162_rn(make_float2(f1.z, f1.w));
    return u.v;
}

// ws layout (bytes):
//   [0)     float partials[3*B*NCH]  (1152)
//   [6144)  int   cnts[2*B]
//   [8192)  unsigned short Ibf[B*L*D]   (8.4 MB, ONLY if ws_size permits)
#define WS_NEED_PRE (8192 + (size_t)B * L * D * 2)

// Fused prep: blocks 0..1023 swizzle I -> Ibf (bf16 fragment order:
// byte offset of (tile rt, half h, lane) = rt*2048 + h*1024 + lane*16);
// blocks 1024..1279 compute mask counts (one block per mask row).
__global__ __launch_bounds__(256) void prep_kernel(
        const float* __restrict__ I, const float* __restrict__ tmask,
        const float* __restrict__ imask, unsigned short* __restrict__ Ibf,
        int* __restrict__ cnts) {
    int blk = blockIdx.x;
    int tid = threadIdx.x;
    __shared__ float red[4];
    if (blk < 1024) {              // b*8 + k
        const float* src = I + (size_t)blk * 64 * D;
        unsigned short* dst = Ibf + (size_t)blk * 4096;
#pragma unroll
        for (int j = 0; j < 2; ++j) {
            int si = tid + j * 256; // 32B source unit: region si>>3, seg si&7
            int r = si >> 3, seg = si & 7;
            const float4* p = (const float4*)(src + (size_t)si * 8);
            bf16x8 v = cvt8(p[0], p[1]);
            int h = seg >> 2, qq = seg & 3;
            int ci = ((r >> 4) * 2 + h) * 64 + qq * 16 + (r & 15);
            *(bf16x8*)(dst + (size_t)ci * 8) = v;
        }
    } else {                       // mask-count row
        int row = blk - 1024;      // 0..2B-1
        float s = 0.f;
        if (row < B) {
            const float* p = tmask + (size_t)row * N;
            for (int i = tid; i < N; i += 256) s += p[i];
        } else {
            const float* p = imask + (size_t)(row - B) * L;
            for (int i = tid; i < L; i += 256) s += p[i];
        }
        for (int off = 32; off > 0; off >>= 1) s += __shfl_down(s, off);
        if ((tid & 63) == 0) red[tid >> 6] = s;
        __syncthreads();
        if (tid == 0)
            cnts[row] = (int)(red[0] + red[1] + red[2] + red[3] + 0.5f);
    }
}

// grid = 3*B*NCH = 1152 blocks x 256 thr. Block (s,b,chunk): 384 tokens
// (6 MFMA token tiles per wave) vs all regions. PRE: B-fragments per-lane
// from pre-swizzled Ibf with DEPTH-2 register prefetch (3-slot ring) —
// rt+2's loads issue before rt's 12 MFMA + 24 fmax (~106 cyc), so ~212 cyc
// of math covers ~200 cyc L2 latency (R11's depth-1/70cyc was exposed).
// No LDS, no main-loop barriers.
template <bool PRE>
__global__ __launch_bounds__(256, 4) void sim_kernel(
        const float* __restrict__ T, const float* __restrict__ I,
        const unsigned short* __restrict__ Ibf, const int* __restrict__ cnts,
        const int* __restrict__ Iimp, const int* __restrict__ Simp,
        float* __restrict__ partials) {
    int blk = blockIdx.x;          // 0..1151
    int chunk = blk % NCH;
    int bs = blk / NCH;            // 0..383
    int b = bs & (B - 1);
    int s = bs >> 7;
    int Tb = b, Ib = b;
    if (s == 1) Tb = Simp[b];
    else if (s == 2) Ib = Iimp[b];
    int ntok = cnts[Tb];
    int nreg = cnts[B + Ib];

    int tid = threadIdx.x;
    int tok0 = chunk * TOKBLK;
    if (tok0 >= ntok) {            // empty chunk: ~100 cycles and gone
        if (tid == 0) partials[blk] = 0.f;
        return;
    }

    int w = tid >> 6;
    int lane = tid & 63;
    int q = lane >> 4;
    int c = lane & 15;

    __shared__ float wsum[4];

    // ---- A fragments: TT token tiles x 2 K-halves (rows clamped to N-1;
    //      clamped rows are always >= ntok so the mask excludes them) ----
    int wt0 = tok0 + w * (TT * 16);
    bf16x8 afrag[TT][2];
#pragma unroll
    for (int tt = 0; tt < TT; ++tt) {
        int row = wt0 + tt * 16 + c;
        if (row > N - 1) row = N - 1;
        const float* trow = T + ((size_t)Tb * N + row) * D;
#pragma unroll
        for (int h = 0; h < 2; ++h) {
            const float4* p = (const float4*)(trow + h * 32 + q * 8);
            afrag[tt][h] = cvt8(p[0], p[1]);
        }
    }

    float mx[TT][4];
#pragma unroll
    for (int tt = 0; tt < TT; ++tt)
#pragma unroll
        for (int i = 0; i < 4; ++i) mx[tt][i] = -3.0e38f;

    int nrt = (nreg + 15) >> 4;
    int prem = nreg & 15;

    if (PRE) {
        const char* imgL = (const char*)(Ibf + (size_t)Ib * L * D) + (size_t)lane * 16;
        // 3-slot register ring: cur (rt), nxt (rt+1), fut (rt+2 in flight)
        bf16x8 c0 = *(const bf16x8*)(imgL);
        bf16x8 c1 = *(const bf16x8*)(imgL + 1024);
        int r1 = (nrt > 1) ? 1 : 0;
        bf16x8 n0 = *(const bf16x8*)(imgL + (size_t)r1 * 2048);
        bf16x8 n1 = *(const bf16x8*)(imgL + (size_t)r1 * 2048 + 1024);
#pragma unroll 1
        for (int rt = 0; rt < nrt; ++rt) {
            int rp = (rt + 2 < nrt) ? rt + 2 : rt;   // clamp: harmless re-read
            const char* pp = imgL + (size_t)rp * 2048;
            bf16x8 f0 = *(const bf16x8*)(pp);
            bf16x8 f1 = *(const bf16x8*)(pp + 1024);
            bool vld = (rt + 1 < nrt) || (prem == 0) || (c < prem);
#pragma unroll
            for (int tt = 0; tt < TT; ++tt) {
                f32x4 acc = {0.f, 0.f, 0.f, 0.f};
                acc = __builtin_amdgcn_mfma_f32_16x16x32_bf16(afrag[tt][0], c0, acc, 0, 0, 0);
                acc = __builtin_amdgcn_mfma_f32_16x16x32_bf16(afrag[tt][1], c1, acc, 0, 0, 0);
                if (vld) {
#pragma unroll
                    for (int i = 0; i < 4; ++i) mx[tt][i] = fmaxf(mx[tt][i], acc[i]);
                }
            }
            c0 = n0; c1 = n1; n0 = f0; n1 = f1;
        }
    } else {
        // fallback (ws too small for Ibf): direct fp32 loads + cvt, no pipeline
        const float* Ibase = I + (size_t)Ib * L * D;
#pragma unroll 1
        for (int rt = 0; rt < nrt; ++rt) {
            int r = rt * 16 + c;                      // r <= 511 always
            const float4* p0 = (const float4*)(Ibase + (size_t)r * D + q * 8);
            bf16x8 b0 = cvt8(p0[0], p0[1]);
            const float4* p1 = (const float4*)(Ibase + (size_t)r * D + 32 + q * 8);
            bf16x8 b1 = cvt8(p1[0], p1[1]);
            bool vld = (rt + 1 < nrt) || (prem == 0) || (c < prem);
#pragma unroll
            for (int tt = 0; tt < TT; ++tt) {
                f32x4 acc = {0.f, 0.f, 0.f, 0.f};
                acc = __builtin_amdgcn_mfma_f32_16x16x32_bf16(afrag[tt][0], b0, acc, 0, 0, 0);
                acc = __builtin_amdgcn_mfma_f32_16x16x32_bf16(afrag[tt][1], b1, acc, 0, 0, 0);
                if (vld) {
#pragma unroll
                    for (int i = 0; i < 4; ++i) mx[tt][i] = fmaxf(mx[tt][i], acc[i]);
                }
            }
        }
    }

    // ---- cross-lane max over 16 region-cols ----
#pragma unroll
    for (int m = 1; m < 16; m <<= 1) {
#pragma unroll
        for (int tt = 0; tt < TT; ++tt)
#pragma unroll
            for (int i = 0; i < 4; ++i)
                mx[tt][i] = fmaxf(mx[tt][i], __shfl_xor(mx[tt][i], m));
    }

    // ---- masked token sum (C layout: row = q*4 + i) ----
    float bsum = 0.f;
    if (c == 0) {
#pragma unroll
        for (int tt = 0; tt < TT; ++tt)
#pragma unroll
            for (int i = 0; i < 4; ++i) {
                int row = wt0 + tt * 16 + q * 4 + i;
                if (row < ntok) bsum += mx[tt][i];
            }
    }
    for (int off = 32; off > 0; off >>= 1) bsum += __shfl_down(bsum, off);
    if (lane == 0) wsum[w] = bsum;
    __syncthreads();
    if (tid == 0)
        partials[blk] = (wsum[0] + wsum[1] + wsum[2] + wsum[3]) / (float)ntok;
}

// 1 block x 384 threads: fold 1152 partials -> 384 sims -> hinge -> loss
__global__ void loss_kernel(const float* __restrict__ partials,
                            float* __restrict__ out) {
    int tid = threadIdx.x;  // 0..383
    __shared__ float simsL[384];
    __shared__ float w6[6];
    simsL[tid] = partials[tid * NCH] + partials[tid * NCH + 1] + partials[tid * NCH + 2];
    __syncthreads();
    float per = 0.f;
    if (tid < B) {
        float anc  = simsL[tid];
        float simp = simsL[B + tid];
        float iimp = simsL[2 * B + tid];
        per = fmaxf(1.f + iimp - anc, 0.f) + fmaxf(1.f + simp - anc, 0.f);
    }
    for (int off = 32; off > 0; off >>= 1) per += __shfl_down(per, off);
    if ((tid & 63) == 0) w6[tid >> 6] = per;
    __syncthreads();
    if (tid == 0)
        out[0] = (w6[0] + w6[1] + w6[2] + w6[3] + w6[4] + w6[5]) / (float)B;
}

extern "C" void kernel_launch(void* const* d_in, const int* in_sizes, int n_in,
                              void* d_out, int out_size, void* d_ws, size_t ws_size,
                              hipStream_t stream) {
    const float* T     = (const float*)d_in[0];
    const float* I     = (const float*)d_in[1];
    const float* tmask = (const float*)d_in[2];
    const float* imask = (const float*)d_in[3];
    const int*   Iimp  = (const int*)d_in[4];
    const int*   Simp  = (const int*)d_in[5];

    float* partials = (float*)d_ws;                          // 1152 f
    int*   cnts     = (int*)((char*)d_ws + 6144);            // 256 i
    unsigned short* Ibf = (unsigned short*)((char*)d_ws + 8192);

    prep_kernel<<<1024 + 2 * B, 256, 0, stream>>>(I, tmask, imask, Ibf, cnts);
    if (ws_size >= WS_NEED_PRE) {
        sim_kernel<true><<<3 * B * NCH, 256, 0, stream>>>(T, I, Ibf, cnts, Iimp, Simp, partials);
    } else {
        sim_kernel<false><<<3 * B * NCH, 256, 0, stream>>>(T, I, Ibf, cnts, Iimp, Simp, partials);
    }
    loss_kernel<<<1, 384, 0, stream>>>(partials, (float*)d_out);
}